// Round 2
// baseline (18301.761 us; speedup 1.0000x reference)
//
#include <hip/hip_runtime.h>

// ConvGRU: 2-layer GRU, B=32, T=512, D=H=512. Inputs/outputs are FP32
// (per reference setup_inputs). Compute path: fp32 -> bf16 conversion once
// per launch, then persistent wavefront-pipelined kernel:
//   superstep s: layer0 @ t=s, layer1 @ t=s-1. 2 grid barriers / superstep.
// Recurrent GEMMs via mfma_f32_16x16x32_bf16, fragments loaded directly from
// global (weights L2-resident). h kept in fp32 master + bf16 shadow.

#define Bn 32
#define Tn 512
#define Dn 512
#define Hn 512
#define KKn 1024
#define NBLK 64
#define NTHR 128
#define NTHREADS (NBLK * NTHR)

typedef __bf16 bf16x8 __attribute__((ext_vector_type(8)));
typedef float floatx4 __attribute__((ext_vector_type(4)));

// Persistent device state (re-initialized every launch inside the kernel).
__device__ float g_h0f[2][Bn * Hn];
__device__ float g_h1f[2][Bn * Hn];
__device__ unsigned short g_h0b[2][Bn * Hn];
__device__ unsigned short g_h1b[2][Bn * Hn];
__device__ float g_u[2][Bn * Hn];
__device__ float g_r[2][Bn * Hn];
// bf16 conversions of the fp32 inputs (filled at launch start, then barrier).
__device__ unsigned short g_xb[Bn * Tn * Dn];          // 16.8 MB
__device__ unsigned short g_Wrb[2 * Hn * KKn];         // 2.1 MB
__device__ unsigned short g_Wub[2 * Hn * KKn];
__device__ unsigned short g_Wob[2 * Hn * KKn];
__device__ unsigned g_arrive = 0;
__device__ unsigned g_epoch = 0;   // monotonic across launches

__device__ __forceinline__ bf16x8 ldb8(const unsigned short* p) {
    return *reinterpret_cast<const bf16x8*>(p);
}
__device__ __forceinline__ unsigned short f2b(float f) {
    union { float f; unsigned u; } v; v.f = f;
    unsigned u = v.u;
    return (unsigned short)((u + 0x7fffu + ((u >> 16) & 1u)) >> 16);  // RNE
}

// Grid barrier: monotonic epoch, agent-scope atomics. All threads fence
// their stores; thread0 arrives & spins; release/acquire on g_epoch.
__device__ __forceinline__ void gbar(unsigned& tgt) {
    __threadfence();
    __syncthreads();
    if (threadIdx.x == 0) {
        tgt++;
        unsigned old = __hip_atomic_fetch_add(&g_arrive, 1u, __ATOMIC_ACQ_REL,
                                              __HIP_MEMORY_SCOPE_AGENT);
        if (old == (unsigned)(NBLK - 1)) {
            __hip_atomic_store(&g_arrive, 0u, __ATOMIC_RELAXED, __HIP_MEMORY_SCOPE_AGENT);
            __hip_atomic_store(&g_epoch, tgt, __ATOMIC_RELEASE, __HIP_MEMORY_SCOPE_AGENT);
        } else {
            while ((int)(__hip_atomic_load(&g_epoch, __ATOMIC_ACQUIRE,
                                           __HIP_MEMORY_SCOPE_AGENT) - tgt) < 0) {
                __builtin_amdgcn_s_sleep(1);
            }
        }
        __threadfence();
    }
    __syncthreads();
}

__device__ __forceinline__ void cvt_arr(const float* __restrict__ src,
                                        unsigned short* __restrict__ dst,
                                        int n, int gtid) {
    for (int i = gtid * 4; i < n; i += NTHREADS * 4) {
        floatx4 v = *reinterpret_cast<const floatx4*>(src + i);
        ushort1 dummy; (void)dummy;
        unsigned short o0 = f2b(v[0]), o1 = f2b(v[1]), o2 = f2b(v[2]), o3 = f2b(v[3]);
        ushort4 pack = make_ushort4(o0, o1, o2, o3);
        *reinterpret_cast<ushort4*>(dst + i) = pack;
    }
}

__global__ __launch_bounds__(NTHR) void gru_persist(
    const float* __restrict__ x,
    const float* __restrict__ Wr, const float* __restrict__ br,
    const float* __restrict__ Wu, const float* __restrict__ bu,
    const float* __restrict__ Wo, const float* __restrict__ bo,
    float* __restrict__ out)
{
    const int tid  = threadIdx.x;
    const int lane = tid & 63;
    const int widx = tid >> 6;
    const int gw   = blockIdx.x * (NTHR / 64) + widx;  // 0..127 global wave id
    const int quad = lane >> 4;                        // 0..3
    const int lo   = lane & 15;                        // 0..15

    unsigned bar_t = 0;
    if (tid == 0)
        bar_t = __hip_atomic_load(&g_epoch, __ATOMIC_RELAXED, __HIP_MEMORY_SCOPE_AGENT);

    // ---- Launch-start: zero h states; convert fp32 inputs to bf16 buffers.
    {
        int gtid = blockIdx.x * NTHR + tid;
        for (int i = gtid; i < 2 * Bn * Hn; i += NTHREADS) {
            (&g_h0f[0][0])[i] = 0.f;
            (&g_h1f[0][0])[i] = 0.f;
            (&g_h0b[0][0])[i] = 0;
            (&g_h1b[0][0])[i] = 0;
        }
        cvt_arr(x,  g_xb,  Bn * Tn * Dn, gtid);
        cvt_arr(Wr, g_Wrb, 2 * Hn * KKn, gtid);
        cvt_arr(Wu, g_Wub, 2 * Hn * KKn, gtid);
        cvt_arr(Wo, g_Wob, 2 * Hn * KKn, gtid);
    }
    gbar(bar_t);

    // ---- Phase A task: (layer, gate u/r, n-tile), covers both 16-row m-tiles.
    const int lA  = gw >> 6;          // 0..1 layer
    const int gA  = (gw >> 5) & 1;    // 0=u, 1=r
    const int n0A = (gw & 31) * 16;
    const unsigned short* WA = (gA ? g_Wrb : g_Wub) + (size_t)lA * Hn * KKn;
    float* outA = (gA ? g_r[lA] : g_u[lA]);
    const float biasA = (gA ? br : bu)[lA * Hn + n0A + lo];

    // ---- Phase B task: (layer, n-tile) x m-tile, o-gate + h-update.
    const int tB  = gw >> 1;          // 0..63
    const int lB  = tB >> 5;
    const int n0B = (tB & 31) * 16;
    const int m0B = (gw & 1) * 16;
    const unsigned short* WB = g_Wob + (size_t)lB * Hn * KKn;
    const float biasB = bo[lB * Hn + n0B + lo];

    for (int s = 0; s <= Tn; ++s) {
        const int cur = s & 1, nxt = cur ^ 1;

        // ================= Phase A: u, r gates =================
        bool actA = (lA == 0) ? (s < Tn) : (s >= 1);
        if (actA) {
            floatx4 acc0 = {0.f, 0.f, 0.f, 0.f};
            floatx4 acc1 = {0.f, 0.f, 0.f, 0.f};
            // x-part (k < 512): layer0 reads x[:, s, :]; layer1 reads h0 state.
            const unsigned short* Ax;
            size_t strA;
            if (lA == 0) { Ax = g_xb + (size_t)s * Dn; strA = (size_t)Tn * Dn; }
            else         { Ax = g_h0b[cur];            strA = Hn; }
            const unsigned short* Wp  = WA + (size_t)(n0A + lo) * KKn + quad * 8;
            const unsigned short* Ap0 = Ax + (size_t)lo * strA + quad * 8;
            const unsigned short* Ap1 = Ax + (size_t)(16 + lo) * strA + quad * 8;
            #pragma unroll 4
            for (int k0 = 0; k0 < Dn; k0 += 32) {
                bf16x8 bfr = ldb8(Wp + k0);
                acc0 = __builtin_amdgcn_mfma_f32_16x16x32_bf16(ldb8(Ap0 + k0), bfr, acc0, 0, 0, 0);
                acc1 = __builtin_amdgcn_mfma_f32_16x16x32_bf16(ldb8(Ap1 + k0), bfr, acc1, 0, 0, 0);
            }
            // h-part (k >= 512): recurrent state of this layer.
            const unsigned short* Hx  = (lA == 0) ? g_h0b[cur] : g_h1b[cur];
            const unsigned short* Hp0 = Hx + (size_t)lo * Hn + quad * 8;
            const unsigned short* Hp1 = Hx + (size_t)(16 + lo) * Hn + quad * 8;
            const unsigned short* Wp2 = Wp + Dn;
            #pragma unroll 4
            for (int k0 = 0; k0 < Hn; k0 += 32) {
                bf16x8 bfr = ldb8(Wp2 + k0);
                acc0 = __builtin_amdgcn_mfma_f32_16x16x32_bf16(ldb8(Hp0 + k0), bfr, acc0, 0, 0, 0);
                acc1 = __builtin_amdgcn_mfma_f32_16x16x32_bf16(ldb8(Hp1 + k0), bfr, acc1, 0, 0, 0);
            }
            // sigmoid, store fp32 gate buffers. D-frag: row=quad*4+r, col=lo.
            #pragma unroll
            for (int r = 0; r < 4; ++r) {
                int b0 = quad * 4 + r;
                float v0 = 1.f / (1.f + __expf(-(acc0[r] + biasA)));
                float v1 = 1.f / (1.f + __expf(-(acc1[r] + biasA)));
                outA[(size_t)b0 * Hn + n0A + lo] = v0;
                outA[(size_t)(16 + b0) * Hn + n0A + lo] = v1;
            }
        }
        gbar(bar_t);

        // ================= Phase B: o gate + h update =================
        bool actB = (lB == 0) ? (s < Tn) : (s >= 1);
        if (actB) {
            floatx4 acc = {0.f, 0.f, 0.f, 0.f};
            const unsigned short* Ax;
            size_t strA;
            if (lB == 0) { Ax = g_xb + (size_t)s * Dn; strA = (size_t)Tn * Dn; }
            else         { Ax = g_h0b[cur];            strA = Hn; }
            const unsigned short* Wp = WB + (size_t)(n0B + lo) * KKn + quad * 8;
            const unsigned short* Ap = Ax + (size_t)(m0B + lo) * strA + quad * 8;
            #pragma unroll 4
            for (int k0 = 0; k0 < Dn; k0 += 32) {
                bf16x8 bfr = ldb8(Wp + k0);
                acc = __builtin_amdgcn_mfma_f32_16x16x32_bf16(ldb8(Ap + k0), bfr, acc, 0, 0, 0);
            }
            // (h*r)-part: build bf16 fragment on the fly from fp32 h and r.
            const float* hfc = (lB == 0) ? g_h0f[cur] : g_h1f[cur];
            const float* rfc = g_r[lB];
            const unsigned short* Wp2 = Wp + Dn;
            size_t rowbase = (size_t)(m0B + lo) * Hn + quad * 8;
            #pragma unroll 2
            for (int k0 = 0; k0 < Hn; k0 += 32) {
                bf16x8 bfr = ldb8(Wp2 + k0);
                floatx4 hv0 = *reinterpret_cast<const floatx4*>(hfc + rowbase + k0);
                floatx4 hv1 = *reinterpret_cast<const floatx4*>(hfc + rowbase + k0 + 4);
                floatx4 rv0 = *reinterpret_cast<const floatx4*>(rfc + rowbase + k0);
                floatx4 rv1 = *reinterpret_cast<const floatx4*>(rfc + rowbase + k0 + 4);
                bf16x8 afr;
                afr[0] = (__bf16)(hv0[0] * rv0[0]); afr[1] = (__bf16)(hv0[1] * rv0[1]);
                afr[2] = (__bf16)(hv0[2] * rv0[2]); afr[3] = (__bf16)(hv0[3] * rv0[3]);
                afr[4] = (__bf16)(hv1[0] * rv1[0]); afr[5] = (__bf16)(hv1[1] * rv1[1]);
                afr[6] = (__bf16)(hv1[2] * rv1[2]); afr[7] = (__bf16)(hv1[3] * rv1[3]);
                acc = __builtin_amdgcn_mfma_f32_16x16x32_bf16(afr, bfr, acc, 0, 0, 0);
            }
            // epilogue: o = tanh(.), h' = h + u*(o-h); write fp32 + bf16 shadows.
            const float* ufc = g_u[lB];
            float* hfn = (lB == 0) ? g_h0f[nxt] : g_h1f[nxt];
            unsigned short* hbn = (lB == 0) ? g_h0b[nxt] : g_h1b[nxt];
            bool fin = (lB == 0) ? (s == Tn - 1) : (s == Tn);
            #pragma unroll
            for (int r = 0; r < 4; ++r) {
                int bb = m0B + quad * 4 + r;
                size_t idx = (size_t)bb * Hn + n0B + lo;
                float o = tanhf(acc[r] + biasB);
                float u = ufc[idx];
                float h = hfc[idx];
                float hn = h + u * (o - h);
                hfn[idx] = hn;
                hbn[idx] = f2b(hn);
                if (fin) out[(size_t)lB * Bn * Hn + idx] = hn;
            }
        }
        gbar(bar_t);
    }
}

extern "C" void kernel_launch(void* const* d_in, const int* in_sizes, int n_in,
                              void* d_out, int out_size, void* d_ws, size_t ws_size,
                              hipStream_t stream) {
    const float* x  = (const float*)d_in[0];
    const float* Wr = (const float*)d_in[1];
    const float* br = (const float*)d_in[2];
    const float* Wu = (const float*)d_in[3];
    const float* bu = (const float*)d_in[4];
    const float* Wo = (const float*)d_in[5];
    const float* bo = (const float*)d_in[6];
    float* out = (float*)d_out;

    gru_persist<<<NBLK, NTHR, 0, stream>>>(x, Wr, br, Wu, bu, Wo, bo, out);
}

// Round 3
// 14703.561 us; speedup vs baseline: 1.2447x; 1.2447x over previous
//
#include <hip/hip_runtime.h>

// ConvGRU: 2-layer GRU, B=32, T=512, D=H=512, fp32 in/out, bf16 MFMA compute.
// Persistent wavefront pipeline: superstep s = layer0@t=s + layer1@t=s-1,
// 2 phases (u,r | o+update) with a grid barrier after each.
// Round-2 redesign: NO agent fences in the steady loop. Cross-block state via
// relaxed agent-scope atomics (device-coherent, no L2 inv/wb); weights and x
// via normal cached loads (L2-hot). Slot-per-block monotonic-epoch barrier.
// h fp32 master lives in wave-private registers; only bf16 shadows in memory.

#define Bn 32
#define Tn 512
#define Dn 512
#define Hn 512
#define KKn 1024
#define NBLK 64
#define NTHR 128
#define NTHREADS (NBLK * NTHR)

typedef __bf16 bf16x8 __attribute__((ext_vector_type(8)));
typedef float floatx4 __attribute__((ext_vector_type(4)));

// ---- persistent device state ----
__device__ unsigned short g_h0b[2][Bn * Hn];   // layer0 h bf16 shadow (ping-pong)
__device__ unsigned short g_h1b[2][Bn * Hn];   // layer1 h bf16 shadow
__device__ unsigned short g_rb[2][Bn * Hn];    // r gate bf16 (per layer)
__device__ float          g_u[2][Bn * Hn];     // u gate fp32 (per layer)
// bf16 conversions of fp32 inputs (filled once per launch, then threadfence).
__device__ unsigned short g_xb[Bn * Tn * Dn];
__device__ unsigned short g_Wrb[2 * Hn * KKn];
__device__ unsigned short g_Wub[2 * Hn * KKn];
__device__ unsigned short g_Wob[2 * Hn * KKn];
// barrier slots: one cacheline-ish apart, monotonically increasing epochs.
__device__ unsigned long long g_slot[NBLK * 8];

__device__ __forceinline__ bf16x8 ldb8(const unsigned short* p) {
    return *reinterpret_cast<const bf16x8*>(p);
}
__device__ __forceinline__ unsigned short f2b(float f) {
    union { float f; unsigned u; } v; v.f = f;
    unsigned u = v.u;
    return (unsigned short)((u + 0x7fffu + ((u >> 16) & 1u)) >> 16);  // RNE
}
__device__ __forceinline__ float b2f(unsigned short b) {
    union { unsigned u; float f; } v; v.u = ((unsigned)b) << 16; return v.f;
}

// ---- relaxed agent-scope atomic helpers (sc0 sc1, no cache maintenance) ----
__device__ __forceinline__ unsigned long long ald8(const void* p) {
    return __hip_atomic_load((const unsigned long long*)p, __ATOMIC_RELAXED,
                             __HIP_MEMORY_SCOPE_AGENT);
}
__device__ __forceinline__ void ast8(void* p, unsigned long long v) {
    __hip_atomic_store((unsigned long long*)p, v, __ATOMIC_RELAXED,
                       __HIP_MEMORY_SCOPE_AGENT);
}
__device__ __forceinline__ float ald4f(const float* p) {
    return __hip_atomic_load(p, __ATOMIC_RELAXED, __HIP_MEMORY_SCOPE_AGENT);
}
__device__ __forceinline__ void ast4f(float* p, float v) {
    __hip_atomic_store(p, v, __ATOMIC_RELAXED, __HIP_MEMORY_SCOPE_AGENT);
}
__device__ __forceinline__ void ast4u(unsigned* p, unsigned v) {
    __hip_atomic_store(p, v, __ATOMIC_RELAXED, __HIP_MEMORY_SCOPE_AGENT);
}

// load 8 bf16 (16B) as two relaxed 8B atomics
__device__ __forceinline__ bf16x8 ald_bf8(const unsigned short* p) {
    union { unsigned long long u; __bf16 b[4]; } a, b;
    a.u = ald8(p);
    b.u = ald8(p + 4);
    bf16x8 r;
    r[0] = a.b[0]; r[1] = a.b[1]; r[2] = a.b[2]; r[3] = a.b[3];
    r[4] = b.b[0]; r[5] = b.b[1]; r[6] = b.b[2]; r[7] = b.b[3];
    return r;
}

// Grid barrier: each block publishes its epoch to its own slot (relaxed,
// device-coherent); wave0's 64 lanes scan all 64 slots in parallel.
// __syncthreads before the store drains every wave's vmcnt (stores visible
// at the coherence point before the slot store issues, in-order VMEM).
__device__ __forceinline__ void gbar(unsigned long long tgt) {
    __syncthreads();
    if (threadIdx.x < 64) {
        if (threadIdx.x == 0)
            ast8(&g_slot[blockIdx.x * 8], tgt);
        while (true) {
            unsigned long long v = ald8(&g_slot[threadIdx.x * 8]);
            if (__all(v >= tgt)) break;
            __builtin_amdgcn_s_sleep(2);
        }
    }
    __syncthreads();
}

__device__ __forceinline__ void cvt_arr(const float* __restrict__ src,
                                        unsigned short* __restrict__ dst,
                                        int n, int gtid) {
    for (int i = gtid * 4; i < n; i += NTHREADS * 4) {
        floatx4 v = *reinterpret_cast<const floatx4*>(src + i);
        ushort4 pack = make_ushort4(f2b(v[0]), f2b(v[1]), f2b(v[2]), f2b(v[3]));
        *reinterpret_cast<ushort4*>(dst + i) = pack;
    }
}

__device__ __forceinline__ floatx4 mfma_bf16(bf16x8 a, bf16x8 b, floatx4 c) {
    return __builtin_amdgcn_mfma_f32_16x16x32_bf16(a, b, c, 0, 0, 0);
}

__global__ __launch_bounds__(NTHR) void gru_persist(
    const float* __restrict__ x,
    const float* __restrict__ Wr, const float* __restrict__ br,
    const float* __restrict__ Wu, const float* __restrict__ bu,
    const float* __restrict__ Wo, const float* __restrict__ bo,
    float* __restrict__ out)
{
    const int tid  = threadIdx.x;
    const int lane = tid & 63;
    const int widx = tid >> 6;
    const int gw   = blockIdx.x * (NTHR / 64) + widx;  // 0..127 global wave id
    const int quad = lane >> 4;                        // 0..3
    const int lo   = lane & 15;                        // 0..15

    // Epoch base: all slots are equal at launch start (monotonic across launches).
    const unsigned long long base = ald8(&g_slot[blockIdx.x * 8]);
    unsigned long long ep = base;

    // ---- Launch-start: zero h shadows (atomic stores — they are only ever
    // accessed device-coherently); convert fp32 inputs to bf16 (normal stores
    // + one threadfence to write back through L2 before the init barrier).
    {
        int gtid = blockIdx.x * NTHR + tid;
        unsigned* h0 = (unsigned*)&g_h0b[0][0];
        unsigned* h1 = (unsigned*)&g_h1b[0][0];
        for (int i = gtid; i < Bn * Hn; i += NTHREADS) {  // 2 buffers * (Bn*Hn)/2 u32
            ast4u(h0 + i, 0u);
            ast4u(h1 + i, 0u);
        }
        cvt_arr(x,  g_xb,  Bn * Tn * Dn, gtid);
        cvt_arr(Wr, g_Wrb, 2 * Hn * KKn, gtid);
        cvt_arr(Wu, g_Wub, 2 * Hn * KKn, gtid);
        cvt_arr(Wo, g_Wob, 2 * Hn * KKn, gtid);
        __threadfence();   // writeback converted data past L2 (once per launch)
    }
    ep++; gbar(ep);

    // ---- Phase A task: (layer, gate u/r, n-tile), covers both 16-row m-tiles.
    const int lA  = gw >> 6;          // 0..1 layer
    const int gA  = (gw >> 5) & 1;    // 0=u, 1=r
    const int n0A = (gw & 31) * 16;
    const unsigned short* WA = (gA ? g_Wrb : g_Wub) + (size_t)lA * Hn * KKn;
    const float biasA = (gA ? br : bu)[lA * Hn + n0A + lo];

    // ---- Phase B task: (layer, n-tile, m-tile): o-gate + h-update.
    const int tB  = gw >> 1;          // 0..63
    const int lB  = tB >> 5;
    const int n0B = (tB & 31) * 16;
    const int m0B = (gw & 1) * 16;
    const unsigned short* WB = g_Wob + (size_t)lB * Hn * KKn;
    const float biasB = bo[lB * Hn + n0B + lo];

    // Wave-private fp32 h master for this wave's 16x16 output tile:
    // element r: (row m0B+quad*4+r, col n0B+lo). Zero-initialized.
    float hreg[4] = {0.f, 0.f, 0.f, 0.f};

    for (int s = 0; s <= Tn; ++s) {
        const int cur = s & 1, nxt = cur ^ 1;

        // ================= Phase A: u, r gates =================
        bool actA = (lA == 0) ? (s < Tn) : (s >= 1);
        if (actA) {
            floatx4 acc0 = {0.f, 0.f, 0.f, 0.f};
            floatx4 acc1 = {0.f, 0.f, 0.f, 0.f};
            const unsigned short* Wp = WA + (size_t)(n0A + lo) * KKn + quad * 8;
            // x-part (k<512): layer0 reads x tile (cached); layer1 reads h0 shadow.
            if (lA == 0) {
                const unsigned short* Ax  = g_xb + (size_t)s * Dn;
                const unsigned short* Ap0 = Ax + (size_t)lo * (Tn * Dn) + quad * 8;
                const unsigned short* Ap1 = Ax + (size_t)(16 + lo) * (Tn * Dn) + quad * 8;
                #pragma unroll 4
                for (int k0 = 0; k0 < Dn; k0 += 32) {
                    bf16x8 bfr = ldb8(Wp + k0);
                    acc0 = mfma_bf16(ldb8(Ap0 + k0), bfr, acc0);
                    acc1 = mfma_bf16(ldb8(Ap1 + k0), bfr, acc1);
                }
            } else {
                const unsigned short* Ax  = g_h0b[cur];
                const unsigned short* Ap0 = Ax + (size_t)lo * Hn + quad * 8;
                const unsigned short* Ap1 = Ax + (size_t)(16 + lo) * Hn + quad * 8;
                #pragma unroll 4
                for (int k0 = 0; k0 < Dn; k0 += 32) {
                    bf16x8 bfr = ldb8(Wp + k0);
                    acc0 = mfma_bf16(ald_bf8(Ap0 + k0), bfr, acc0);
                    acc1 = mfma_bf16(ald_bf8(Ap1 + k0), bfr, acc1);
                }
            }
            // h-part (k>=512): own layer's recurrent shadow (device-coherent).
            {
                const unsigned short* Hx  = (lA == 0) ? g_h0b[cur] : g_h1b[cur];
                const unsigned short* Hp0 = Hx + (size_t)lo * Hn + quad * 8;
                const unsigned short* Hp1 = Hx + (size_t)(16 + lo) * Hn + quad * 8;
                const unsigned short* Wp2 = Wp + Dn;
                #pragma unroll 4
                for (int k0 = 0; k0 < Hn; k0 += 32) {
                    bf16x8 bfr = ldb8(Wp2 + k0);
                    acc0 = mfma_bf16(ald_bf8(Hp0 + k0), bfr, acc0);
                    acc1 = mfma_bf16(ald_bf8(Hp1 + k0), bfr, acc1);
                }
            }
            // epilogue: sigmoid; u -> fp32 atomics; r -> packed bf16 atomics.
            float* up = g_u[lA];
            unsigned short* rp = g_rb[lA];
            #pragma unroll
            for (int r = 0; r < 4; ++r) {
                int b0 = quad * 4 + r;
                float v0 = 1.f / (1.f + __expf(-(acc0[r] + biasA)));
                float v1 = 1.f / (1.f + __expf(-(acc1[r] + biasA)));
                size_t i0 = (size_t)b0 * Hn + n0A + lo;
                size_t i1 = (size_t)(16 + b0) * Hn + n0A + lo;
                if (gA == 0) {
                    ast4f(up + i0, v0);
                    ast4f(up + i1, v1);
                } else {
                    unsigned w0 = f2b(v0), w1 = f2b(v1);
                    unsigned p0 = __shfl_xor((int)w0, 1);
                    unsigned p1 = __shfl_xor((int)w1, 1);
                    if ((lo & 1) == 0) {
                        ast4u((unsigned*)(rp + i0), w0 | (p0 << 16));
                        ast4u((unsigned*)(rp + i1), w1 | (p1 << 16));
                    }
                }
            }
        }
        ep++; gbar(ep);

        // ================= Phase B: o gate + h update =================
        bool actB = (lB == 0) ? (s < Tn) : (s >= 1);
        if (actB) {
            floatx4 acc = {0.f, 0.f, 0.f, 0.f};
            const unsigned short* Wp = WB + (size_t)(n0B + lo) * KKn + quad * 8;
            // x-part
            if (lB == 0) {
                const unsigned short* Ap = g_xb + (size_t)s * Dn
                                         + (size_t)(m0B + lo) * (Tn * Dn) + quad * 8;
                #pragma unroll 4
                for (int k0 = 0; k0 < Dn; k0 += 32)
                    acc = mfma_bf16(ldb8(Ap + k0), ldb8(Wp + k0), acc);
            } else {
                const unsigned short* Ap = g_h0b[cur] + (size_t)(m0B + lo) * Hn + quad * 8;
                #pragma unroll 4
                for (int k0 = 0; k0 < Dn; k0 += 32)
                    acc = mfma_bf16(ald_bf8(Ap + k0), ldb8(Wp + k0), acc);
            }
            // (h*r)-part from bf16 shadows (both device-coherent).
            {
                const unsigned short* hsh = (lB == 0) ? g_h0b[cur] : g_h1b[cur];
                const unsigned short* rsh = g_rb[lB];
                const unsigned short* Wp2 = Wp + Dn;
                size_t rowbase = (size_t)(m0B + lo) * Hn + quad * 8;
                #pragma unroll 2
                for (int k0 = 0; k0 < Hn; k0 += 32) {
                    bf16x8 hv = ald_bf8(hsh + rowbase + k0);
                    bf16x8 rv = ald_bf8(rsh + rowbase + k0);
                    bf16x8 afr;
                    #pragma unroll
                    for (int j = 0; j < 8; ++j)
                        afr[j] = (__bf16)((float)hv[j] * (float)rv[j]);
                    acc = mfma_bf16(afr, ldb8(Wp2 + k0), acc);
                }
            }
            // epilogue: o=tanh; h' = h + u*(o-h) on register master; publish shadow.
            const float* up = g_u[lB];
            unsigned short* hbn = ((lB == 0) ? g_h0b[nxt] : g_h1b[nxt]);
            bool fin = (lB == 0) ? (s == Tn - 1) : (s == Tn);
            #pragma unroll
            for (int r = 0; r < 4; ++r) {
                int bb = m0B + quad * 4 + r;
                size_t idx = (size_t)bb * Hn + n0B + lo;
                float o = tanhf(acc[r] + biasB);
                float u = ald4f(up + idx);
                float h = hreg[r];
                float hn = h + u * (o - h);
                hreg[r] = hn;
                unsigned w = f2b(hn);
                unsigned p = __shfl_xor((int)w, 1);
                if ((lo & 1) == 0)
                    ast4u((unsigned*)(hbn + idx), w | (p << 16));
                if (fin) out[(size_t)lB * Bn * Hn + idx] = hn;
            }
        }
        ep++; gbar(ep);
    }
}

extern "C" void kernel_launch(void* const* d_in, const int* in_sizes, int n_in,
                              void* d_out, int out_size, void* d_ws, size_t ws_size,
                              hipStream_t stream) {
    const float* x  = (const float*)d_in[0];
    const float* Wr = (const float*)d_in[1];
    const float* br = (const float*)d_in[2];
    const float* Wu = (const float*)d_in[3];
    const float* bu = (const float*)d_in[4];
    const float* Wo = (const float*)d_in[5];
    const float* bo = (const float*)d_in[6];
    float* out = (float*)d_out;

    gru_persist<<<NBLK, NTHR, 0, stream>>>(x, Wr, br, Wu, bu, Wo, bo, out);
}